// Round 9
// baseline (188.920 us; speedup 1.0000x reference)
//
#include <hip/hip_runtime.h>
#include <hip/hip_fp16.h>

#define HH 256
#define WW 256
#define KK 81
#define PLANE (HH * WW)
#define SLK 10            // row AND col halo
#define TR 21             // tile rows: [ho-10, ho+10]
#define TC 150            // tile cols: 128-px strip + 10 halo each side + 2
#define TAB (TR * TC)     // 3150 cells
#define RD 8              // ring depth (taps in flight per wave)

// Pack [B,3,H,W] fp32 -> [B,H,W] ushort4 of fp16 (c0,c1,c2,0).
__global__ __launch_bounds__(256) void pack_kernel(const float* __restrict__ in,
                                                   ushort4* __restrict__ img) {
    int idx = blockIdx.x * 256 + threadIdx.x;  // b*PLANE + pix
    int b = idx >> 16;
    int pix = idx & 0xFFFF;
    const float* base = in + (size_t)b * 3 * PLANE + pix;
    _Float16 h0 = (_Float16)base[0];
    _Float16 h1 = (_Float16)base[PLANE];
    _Float16 h2 = (_Float16)base[2 * PLANE];
    ushort4 u;
    u.x = __builtin_bit_cast(unsigned short, h0);
    u.y = __builtin_bit_cast(unsigned short, h1);
    u.z = __builtin_bit_cast(unsigned short, h2);
    u.w = 0;
    img[idx] = u;
}

__device__ __forceinline__ void acc3(float w, unsigned int pa, unsigned int pb,
                                     float& ax, float& ay, float& az) {
    __half2 ha = __builtin_bit_cast(__half2, pa);
    __half2 hb = __builtin_bit_cast(__half2, pb);
    ax = fmaf(w, __low2float(ha), ax);   // v_fma_mix_f32 (lo)
    ay = fmaf(w, __high2float(ha), ay);  // v_fma_mix_f32 (hi)
    az = fmaf(w, __low2float(hb), az);
}

// Async stage of one wave's 256 B channel-row segment into LDS (4 B/lane,
// zero register dependency; tracked by this wave's vmcnt only).
__device__ __forceinline__ void gload_lds4(const float* g, float* l) {
    __builtin_amdgcn_global_load_lds(
        (const __attribute__((address_space(1))) unsigned int*)g,
        (__attribute__((address_space(3))) unsigned int*)l,
        4, 0, 0);
}

// CLEAN DEEP-PIPELINE kernel (round 9) == round 6 MINUS the poison fences.
// Block = 128-px half-row, 2 waves; wave = 64-px strip, all 81 taps.
//
// Each wave streams its own (dy,dx,m) rows via global_load_lds into a
// PRIVATE 8-slot LDS ring. Pacing is ONE counted `s_waitcnt vmcnt(21)` per
// tap (3 loads/tap x 8 slots = 24 outstanding; vmcnt retires in issue
// order, so <=21 means tap j's 3 have landed). NO lgkmcnt(0), NO
// sched_barrier: slot-data consumption is ordered by natural use-def
// (compiler emits the minimal lgkm wait), and the slot re-issue DMA cannot
// be hoisted above the slot reads (same LDS address, may-alias).
// r6 proved correctness of this exact ring; its 22us regression was the
// per-tap full-LDS-pipe drain, removed here.
// In-flight per CU: 8 waves x 24 DMA x 256 B ~ 49 KB (~750 lines) vs the
// ~40-line invariant measured across rounds 0-8.
__global__ __launch_bounds__(128, 2) void dcn_kernel(
    const ushort4* __restrict__ img,
    const float* __restrict__ offset,
    const float* __restrict__ mask,
    const float* __restrict__ weight,
    const float* __restrict__ bias,
    float* __restrict__ out) {
    __shared__ uint2 tile[TAB];              // 25200 B zero-padded fp16 image
    __shared__ float ring[2][RD][192];       // 12288 B: [wave][slot][dy|dx|m]

    const int t = threadIdx.x;               // local col in [0,128)
    const int wv = t >> 6;
    const int l = t & 63;
    const int b = blockIdx.y;
    const int ho = blockIdx.x >> 1;          // output row
    const int xo = (blockIdx.x & 1) * 128;   // strip origin col
    const int yb = ho - SLK;
    const ushort4* ib = img + (size_t)b * PLANE;

    // wave-strip base into offset/mask rows (per-lane addr = base + l)
    const float* orow = offset + (size_t)b * 2 * KK * PLANE + (size_t)ho * WW + xo + wv * 64;
    const float* mrow = mask + (size_t)b * KK * PLANE + (size_t)ho * WW + xo + wv * 64;

    // ---- prologue: issue taps 0..RD-1 into the ring (drain under staging) ----
#pragma unroll
    for (int j = 0; j < RD; ++j) {
        float* slot = &ring[wv][j][0];
        gload_lds4(orow + (size_t)(2 * j) * PLANE + l, slot);
        gload_lds4(orow + (size_t)(2 * j + 1) * PLANE + l, slot + 64);
        gload_lds4(mrow + (size_t)j * PLANE + l, slot + 128);
    }

    // ---- stage zero-padded tile: 3150 cells, 25 iters of 128 threads ----
    for (int i = 0; i < 25; ++i) {
        int cid = t + i * 128;
        if (cid < TAB) {
            int r = cid / TC;
            int c = cid - r * TC;
            int iy = yb + r;
            int ix = xo - SLK + c;
            unsigned int pa = 0, pb = 0;
            if (((unsigned)iy < (unsigned)HH) & ((unsigned)ix < (unsigned)WW)) {
                ushort4 u = ib[iy * WW + ix];
                pa = (unsigned int)u.x | ((unsigned int)u.y << 16);
                pb = (unsigned int)u.z;
            }
            tile[cid] = make_uint2(pa, pb);
        }
    }
    __syncthreads();                         // drains vmcnt: taps 0..7 landed

    const float wof = (float)t;
    float ax = 0.f, ay = 0.f, az = 0.f;
    bool escaped = false;

    // ---- main loop: taps 0..72, steady-state 24 loads (8 taps) in flight ----
#pragma unroll 1
    for (int j = 0; j < 73; ++j) {
        asm volatile("s_waitcnt vmcnt(21)" ::: "memory");  // tap j's 3 landed

        const float* slot = &ring[wv][j & (RD - 1)][0];
        float dy = slot[l];
        float dx = slot[64 + l];
        float m = slot[128 + l];
        float wkv = weight[j];               // wave-uniform s_load

        // re-issue this slot for tap j+8 (after the reads in program order;
        // same-address may-alias keeps the scheduler from hoisting it)
        {
            float* ns = &ring[wv][j & (RD - 1)][0];
            gload_lds4(orow + (size_t)(2 * (j + RD)) * PLANE + l, ns);
            gload_lds4(orow + (size_t)(2 * (j + RD) + 1) * PLANE + l, ns + 64);
            gload_lds4(mrow + (size_t)(j + RD) * PLANE + l, ns + 128);
        }

        const int ky = j / 9;
        const int kxi = j - ky * 9;

        float yf = floorf(dy);
        float wy = dy - yf;                  // fract(dy) == fract(py)
        int r0 = (int)yf + ky + (SLK - 4);   // floor(py) - yb

        float px = dx + wof;
        float xf = floorf(px);
        float wx = px - xf;
        int c0 = (int)xf + kxi + (SLK - 4);  // floor(px) - xb (local)

        bool ok = ((unsigned)r0 < (unsigned)(TR - 1)) &
                  ((unsigned)c0 < (unsigned)(TC - 1));
        escaped |= !ok;
        float mw = (ok ? m : 0.f) * wkv;     // cndmask; zero kills tap

        float w1y = wy * mw, w0y = mw - w1y; // validity via zero-padded data
        float u1 = 1.f - wx;
        float w00 = w0y * u1, w01 = w0y * wx;
        float w10 = w1y * u1, w11 = w1y * wx;

        int r0c = min(max(r0, 0), TR - 2);   // LDS read always safe
        int c0c = min(max(c0, 0), TC - 2);
        const uint2* p = &tile[r0c * TC + c0c];
        uint2 q00 = p[0];
        uint2 q01 = p[1];
        uint2 q10 = p[TC];
        uint2 q11 = p[TC + 1];

        acc3(w00, q00.x, q00.y, ax, ay, az);
        acc3(w01, q01.x, q01.y, ax, ay, az);
        acc3(w10, q10.x, q10.y, ax, ay, az);
        acc3(w11, q11.x, q11.y, ax, ay, az);
    }

    // ---- tail: taps 73..80 already in flight; one drain, then consume ----
    asm volatile("s_waitcnt vmcnt(0)" ::: "memory");
#pragma unroll 1
    for (int j = 73; j < KK; ++j) {
        const float* slot = &ring[wv][j & (RD - 1)][0];
        float dy = slot[l];
        float dx = slot[64 + l];
        float m = slot[128 + l];
        float wkv = weight[j];

        const int ky = j / 9;
        const int kxi = j - ky * 9;

        float yf = floorf(dy);
        float wy = dy - yf;
        int r0 = (int)yf + ky + (SLK - 4);
        float px = dx + wof;
        float xf = floorf(px);
        float wx = px - xf;
        int c0 = (int)xf + kxi + (SLK - 4);

        bool ok = ((unsigned)r0 < (unsigned)(TR - 1)) &
                  ((unsigned)c0 < (unsigned)(TC - 1));
        escaped |= !ok;
        float mw = (ok ? m : 0.f) * wkv;

        float w1y = wy * mw, w0y = mw - w1y;
        float u1 = 1.f - wx;
        float w00 = w0y * u1, w01 = w0y * wx;
        float w10 = w1y * u1, w11 = w1y * wx;

        int r0c = min(max(r0, 0), TR - 2);
        int c0c = min(max(c0, 0), TC - 2);
        const uint2* p = &tile[r0c * TC + c0c];
        uint2 q00 = p[0];
        uint2 q01 = p[1];
        uint2 q10 = p[TC];
        uint2 q11 = p[TC + 1];

        acc3(w00, q00.x, q00.y, ax, ay, az);
        acc3(w01, q01.x, q01.y, ax, ay, az);
        acc3(w10, q10.x, q10.y, ax, ay, az);
        acc3(w11, q11.x, q11.y, ax, ay, az);
    }

    // ---- rare escapes: exact clamped + validity-masked global redo ----
    if (__builtin_expect(escaped, 0)) {
#pragma unroll 1
        for (int k = 0; k < KK; ++k) {
            int ky = k / 9;
            int kxi = k - ky * 9;
            float dy = orow[(size_t)(2 * k) * PLANE + l];
            float dx = orow[(size_t)(2 * k + 1) * PLANE + l];
            float m = mrow[(size_t)k * PLANE + l];

            float yf = floorf(dy);
            int r0 = (int)yf + ky + (SLK - 4);
            float px = dx + wof;
            float xf = floorf(px);
            int c0 = (int)xf + kxi + (SLK - 4);
            bool ok = ((unsigned)r0 < (unsigned)(TR - 1)) &
                      ((unsigned)c0 < (unsigned)(TC - 1));
            if (ok) continue;                // pass 1 handled it

            // absolute coords, zero-pad semantics
            float wy = dy - yf;
            float wx = px - xf;
            int y0 = (int)yf + ho - 4 + ky;
            int x0 = (int)xf + xo + kxi - 4;
            int y1 = y0 + 1, x1 = x0 + 1;
            float mw = m * weight[k];
            float va0 = ((unsigned)y0 < (unsigned)HH) ? 1.f : 0.f;
            float va1 = ((unsigned)y1 < (unsigned)HH) ? 1.f : 0.f;
            float vb0 = ((unsigned)x0 < (unsigned)WW) ? 1.f : 0.f;
            float vb1 = ((unsigned)x1 < (unsigned)WW) ? 1.f : 0.f;
            float w1y = wy * mw, w0y = mw - w1y;
            float w00 = w0y * (1.f - wx) * va0 * vb0;
            float w01 = w0y * wx * va0 * vb1;
            float w10 = w1y * (1.f - wx) * va1 * vb0;
            float w11 = w1y * wx * va1 * vb1;
            int y0c = min(max(y0, 0), HH - 1);
            int y1c = min(max(y1, 0), HH - 1);
            int x0c = min(max(x0, 0), WW - 1);
            int x1c = min(max(x1, 0), WW - 1);
            ushort4 g00 = ib[y0c * WW + x0c];
            ushort4 g01 = ib[y0c * WW + x1c];
            ushort4 g10 = ib[y1c * WW + x0c];
            ushort4 g11 = ib[y1c * WW + x1c];
            acc3(w00, (unsigned int)g00.x | ((unsigned int)g00.y << 16), g00.z, ax, ay, az);
            acc3(w01, (unsigned int)g01.x | ((unsigned int)g01.y << 16), g01.z, ax, ay, az);
            acc3(w10, (unsigned int)g10.x | ((unsigned int)g10.y << 16), g10.z, ax, ay, az);
            acc3(w11, (unsigned int)g11.x | ((unsigned int)g11.y << 16), g11.z, ax, ay, az);
        }
    }

    // ---- direct write-out ----
    float bs = bias[0];
    float* ob = out + (size_t)b * 3 * PLANE + (size_t)ho * WW + xo + t;
    ob[0] = ax + bs;
    ob[PLANE] = ay + bs;
    ob[2 * PLANE] = az + bs;
}

extern "C" void kernel_launch(void* const* d_in, const int* in_sizes, int n_in,
                              void* d_out, int out_size, void* d_ws, size_t ws_size,
                              hipStream_t stream) {
    const float* input = (const float*)d_in[0];
    const float* offset = (const float*)d_in[1];
    const float* mask = (const float*)d_in[2];
    const float* weight = (const float*)d_in[3];
    const float* bias = (const float*)d_in[4];
    float* out = (float*)d_out;

    const int B = in_sizes[0] / (3 * PLANE);  // 2
    ushort4* img = (ushort4*)d_ws;            // 1 MB packed fp16 image

    pack_kernel<<<B * PLANE / 256, 256, 0, stream>>>(input, img);
    dim3 grid(HH * 2, B);                     // 2 half-row blocks per row
    dcn_kernel<<<grid, 128, 0, stream>>>(img, offset, mask, weight, bias, out);
}